// Round 1
// baseline (178.109 us; speedup 1.0000x reference)
//
#include <hip/hip_runtime.h>
#include <math.h>

// Problem constants
#define BATCH 16
#define SEQ   4096
#define HIN   128
#define NST   256
#define HOUT  128
#define CL    32              // chunk length for scan
#define NC    (SEQ/CL)        // 128 chunks
#define ROWS  (BATCH*SEQ)     // 65536
#define KTOT  640             // W K layout: 256 re + 256 im + 128 u
#define NPRE  512             // preL row width: [x_re 256 | x_im 256]

typedef __attribute__((ext_vector_type(8))) short short8;
typedef __attribute__((ext_vector_type(4))) float f32x4;

__device__ inline unsigned short f2bf(float f) {
  union { float f; unsigned u; } v; v.f = f;
  unsigned r = v.u + 0x7FFFu + ((v.u >> 16) & 1u);   // RNE
  return (unsigned short)(r >> 16);
}
__device__ inline float bf2f(unsigned short s) {
  union { unsigned u; float f; } v; v.u = ((unsigned)s) << 16;
  return v.f;
}
__device__ inline float bits2f(unsigned u) {
  union { unsigned u; float f; } v; v.u = u; return v.f;
}

// ------------------------------------------------------------- prep --------
// Wb rows PERMUTED: row r: g=r>>7, w=r&127; n = g*64 + (w&63);
//   w<64 -> gamma*B_re[n], else gamma*B_im[n].
// W = [C_re | -C_im | D] bf16 [128][640].
// lamPk[j][n] = packed bf16 (re lo, im hi) of lambda_n^j, j=0..31.
__global__ __launch_bounds__(256) void k_prep(
    const float* __restrict__ nu_log, const float* __restrict__ theta_log,
    const float* __restrict__ gamma_log,
    const float* __restrict__ Bre, const float* __restrict__ Bim,
    const float* __restrict__ Cre, const float* __restrict__ Cim,
    const float* __restrict__ Dm,
    float* __restrict__ lamre, float* __restrict__ lamim,
    unsigned* __restrict__ lamPk,
    unsigned short* __restrict__ Wb, unsigned short* __restrict__ W) {
  int idx = blockIdx.x*256 + threadIdx.x;
  if (idx < NST) {
    float lm = expf(-expf(nu_log[idx]));
    float th = expf(theta_log[idx]);
    float lr = lm * cosf(th), li = lm * sinf(th);
    lamre[idx] = lr; lamim[idx] = li;
    float pr = 1.f, pi = 0.f;
    for (int j = 0; j < CL; ++j) {
      lamPk[j*NST + idx] = ((unsigned)f2bf(pi) << 16) | (unsigned)f2bf(pr);
      float nr = pr*lr - pi*li;
      float ni = pr*li + pi*lr;
      pr = nr; pi = ni;
    }
  }
  if (idx < 512*HIN) {
    int r = idx >> 7, h = idx & 127;
    int g = r >> 7;
    int w = r & 127;
    int n = g*64 + (w & 63);
    float gm = expf(gamma_log[n]);
    float v = (w < 64) ? Bre[n*HIN + h] : Bim[n*HIN + h];
    Wb[idx] = f2bf(gm * v);
  }
  if (idx < HOUT*KTOT) {
    int o = idx / KTOT, k = idx - o*KTOT;
    float v;
    if (k < NST)        v =  Cre[o*NST + k];
    else if (k < 2*NST) v = -Cim[o*NST + (k - NST)];
    else                v =  Dm[o*HIN + (k - 2*NST)];
    W[idx] = f2bf(v);
  }
}

// -------- bu GEMM (MFMA) + fused local-prefix + chunk-carry epilogue -------
// grid ROWS/64 = 1024 (was 512: grid-limited to 2 blocks/CU, 17% occupancy).
// Block: 64 rows x 512 cols (4 col-groups), 3 blocks/CU (52 KB LDS).
// Reads u f32 directly (converts during staging). Emits preL (bf16 local
// prefix states) + S_re/S_im (f32 chunk carries). bu never materialized.
union SharedBu {
  unsigned short B[128][136];   // 34.8 KB group staging
  float stg[2][32][132];        // 33.8 KB carry stage (2 chunks)
};
__global__ __launch_bounds__(256, 3) void k_bu(
    const float* __restrict__ u, const unsigned short* __restrict__ Wb,
    const float* __restrict__ lamre, const float* __restrict__ lamim,
    unsigned short* __restrict__ preL,
    float* __restrict__ S_re, float* __restrict__ S_im) {
  __shared__ unsigned short Asl[64][136];   // resident whole kernel
  __shared__ SharedBu sh;
  int tid = threadIdx.x;
  int row0 = blockIdx.x * 64;
  int wid = tid >> 6, lane = tid & 63;
  int lm = lane & 15, lq = lane >> 4;
  int m0 = (wid >> 1) * 32, n0 = (wid & 1) * 64;
  int ck = wid >> 1;                  // chunk within block owned by this wave
  int b = row0 >> 12;                 // / SEQ
  int cbase = (row0 & 4095) >> 5;     // / CL
  // stage A: 64 rows x 128 f32 -> bf16
#pragma unroll
  for (int cc = 0; cc < 4; ++cc) {
    int ch = cc*256 + tid;
    int r = ch >> 4, h0 = (ch & 15) * 8;
    const float* src = u + (size_t)(row0 + r)*HIN + h0;
    float4 v0 = *(const float4*)src;
    float4 v1 = *(const float4*)(src + 4);
    unsigned short o[8];
    o[0]=f2bf(v0.x); o[1]=f2bf(v0.y); o[2]=f2bf(v0.z); o[3]=f2bf(v0.w);
    o[4]=f2bf(v1.x); o[5]=f2bf(v1.y); o[6]=f2bf(v1.z); o[7]=f2bf(v1.w);
    *(short8*)&Asl[r][h0] = *(const short8*)o;
  }
  for (int g = 0; g < 4; ++g) {
    __syncthreads();    // A ready (g=0) / prior scan's stg reads done (g>0)
#pragma unroll
    for (int cc = 0; cc < 8; ++cc) {
      int ch = cc*256 + tid;
      int r = ch >> 4, h0 = (ch & 15) * 8;
      *(short8*)&sh.B[r][h0] = *(const short8*)&Wb[(size_t)(g*128 + r)*HIN + h0];
    }
    __syncthreads();
    f32x4 acc[2][4];
#pragma unroll
    for (int i = 0; i < 2; ++i)
#pragma unroll
      for (int j = 0; j < 4; ++j) acc[i][j] = (f32x4)0.f;
#pragma unroll
    for (int ks = 0; ks < 4; ++ks) {
      int k0 = ks*32 + lq*8;
      short8 a[2], bb[4];
#pragma unroll
      for (int i = 0; i < 2; ++i) a[i] = *(const short8*)&Asl[m0 + i*16 + lm][k0];
#pragma unroll
      for (int j = 0; j < 4; ++j) bb[j] = *(const short8*)&sh.B[n0 + j*16 + lm][k0];
#pragma unroll
      for (int i = 0; i < 2; ++i)
#pragma unroll
        for (int j = 0; j < 4; ++j)
          acc[i][j] = __builtin_amdgcn_mfma_f32_16x16x32_bf16(a[i], bb[j], acc[i][j], 0, 0, 0);
    }
    __syncthreads();   // B reads done before stg overwrite (union)
    // stage acc to LDS: rows 0..63 = 2 chunks of 32
#pragma unroll
    for (int i = 0; i < 2; ++i)
#pragma unroll
      for (int j = 0; j < 4; ++j)
#pragma unroll
        for (int r = 0; r < 4; ++r) {
          int trow = i*16 + lq*4 + r;            // 0..31 within chunk
          sh.stg[ck][trow][n0 + j*16 + lm] = acc[i][j][r];
        }
    __syncthreads();
    if (tid < 128) {
      int buf = tid >> 6, nl = tid & 63;
      int ng = g*64 + nl;
      float lr = lamre[ng], li = lamim[ng];
      float rr[CL], ri[CL];
#pragma unroll
      for (int t = 0; t < CL; ++t) {
        rr[t] = sh.stg[buf][t][nl];
        ri[t] = sh.stg[buf][t][64 + nl];
      }
      int rowb = row0 + buf*32;
      unsigned short* pl = preL + (size_t)rowb*NPRE;
      float sr = 0.f, si = 0.f;
#pragma unroll
      for (int t = 0; t < CL; ++t) {
        pl[ng]       = f2bf(sr);     // local prefix BEFORE step t
        pl[NST + ng] = f2bf(si);
        float nr = lr*sr - li*si + rr[t];
        float ni = lr*si + li*sr + ri[t];
        sr = nr; si = ni; pl += NPRE;
      }
      int c = cbase + buf;
      int idx = (b*NC + c)*NST + ng;
      S_re[idx] = sr; S_im[idx] = si;
    }
  }
}

// ---------------- two-level scan of chunk carries -> X0 --------------------
// level 1: carries over groups of 16 chunks. grid BATCH*8, block 256.
// Loads explicitly hoisted: 16 independent loads issue together (one memory
// round-trip) instead of serializing inside the dependent FMA chain.
__global__ __launch_bounds__(256) void k_carry2(
    const float* __restrict__ S_re, const float* __restrict__ S_im,
    const float* __restrict__ lamre, const float* __restrict__ lamim,
    float* __restrict__ G_re, float* __restrict__ G_im) {
  int blk = blockIdx.x;
  int b = blk >> 3, g = blk & 7;
  int n = threadIdx.x;
  float ar = lamre[n], ai = lamim[n];
#pragma unroll
  for (int s = 0; s < 5; ++s) { float nr = ar*ar - ai*ai, ni = 2.f*ar*ai; ar = nr; ai = ni; } // lam^32
  float sre[16], sim[16];
#pragma unroll
  for (int cc = 0; cc < 16; ++cc) {
    int idx = (b*NC + g*16 + cc)*NST + n;
    sre[cc] = S_re[idx]; sim[cc] = S_im[idx];
  }
  float tr = 0.f, ti = 0.f;
#pragma unroll
  for (int cc = 0; cc < 16; ++cc) {
    float nr = ar*tr - ai*ti + sre[cc];
    float ni = ar*ti + ai*tr + sim[cc];
    tr = nr; ti = ni;
  }
  int gi = (b*8 + g)*NST + n;
  G_re[gi] = tr; G_im[gi] = ti;
}

// level 2: group prefix then per-chunk X0 (packed bf16). grid BATCH*8.
__global__ __launch_bounds__(256) void k_final(
    const float* __restrict__ S_re, const float* __restrict__ S_im,
    const float* __restrict__ G_re, const float* __restrict__ G_im,
    const float* __restrict__ lamre, const float* __restrict__ lamim,
    unsigned* __restrict__ X0Pk) {
  int blk = blockIdx.x;
  int b = blk >> 3, g = blk & 7;
  int n = threadIdx.x;
  float ar = lamre[n], ai = lamim[n];
#pragma unroll
  for (int s = 0; s < 5; ++s) { float nr = ar*ar - ai*ai, ni = 2.f*ar*ai; ar = nr; ai = ni; } // lam^32
  float a5r = ar, a5i = ai;
#pragma unroll
  for (int s = 0; s < 4; ++s) { float nr = a5r*a5r - a5i*a5i, ni = 2.f*a5r*a5i; a5r = nr; a5i = ni; } // lam^512
  // prefetch group carries (g is block-uniform -> uniform branches)
  float gr_[7], gi_[7];
#pragma unroll
  for (int j = 0; j < 7; ++j) {
    if (j < g) { int gi2 = (b*8 + j)*NST + n; gr_[j] = G_re[gi2]; gi_[j] = G_im[gi2]; }
    else       { gr_[j] = 0.f; gi_[j] = 0.f; }
  }
  float pr = 0.f, pi = 0.f;
#pragma unroll
  for (int j = 0; j < 7; ++j) {
    if (j < g) {
      float nr = a5r*pr - a5i*pi + gr_[j];
      float ni = a5r*pi + a5i*pr + gi_[j];
      pr = nr; pi = ni;
    }
  }
  // prefetch S for this group, then run the dependent chain
  float sre[16], sim[16];
#pragma unroll
  for (int cc = 0; cc < 16; ++cc) {
    int idx = (b*NC + g*16 + cc)*NST + n;
    sre[cc] = S_re[idx]; sim[cc] = S_im[idx];
  }
  float xr = pr, xi = pi;
#pragma unroll
  for (int cc = 0; cc < 16; ++cc) {
    int idx = (b*NC + g*16 + cc)*NST + n;
    X0Pk[idx] = ((unsigned)f2bf(xi) << 16) | (unsigned)f2bf(xr);
    float nr = ar*xr - ai*xi + sre[cc];
    float ni = ar*xi + ai*xr + sim[cc];
    xr = nr; xi = ni;
  }
}

// ------- output GEMM: A-fragments direct from global + in-reg fix-up -------
// y[64 rows][128 o] = [fix(preL) | u] @ W^T.   grid ROWS/64 = 1024
// (was 128-row blocks / 512 grid: 2 blocks/CU grid-limited; now 4 blocks/CU).
// fix: pre[row][n] = preL[row][n] + lam^j * X0[chunk(row)][n], j = row & 31.
// Wave wid owns rows [wid*16, wid*16+16). Only B staged in LDS (34.8 KB).
__global__ __launch_bounds__(256, 4) void k_out2(
    const unsigned short* __restrict__ preL, const float* __restrict__ u,
    const unsigned short* __restrict__ W,
    const unsigned* __restrict__ lamPk, const unsigned* __restrict__ X0Pk,
    float* __restrict__ y) {
  __shared__ unsigned short Bsl[128][136];
  int tid = threadIdx.x;
  int row0 = blockIdx.x * 64;
  int wid = tid >> 6, lane = tid & 63;
  int lm = lane & 15, lq = lane >> 4;
  int m0 = wid * 16;
  f32x4 acc[8];
#pragma unroll
  for (int j = 0; j < 8; ++j) acc[j] = (f32x4)0.f;
  int grow = row0 + m0 + lm;
  int j32 = grow & 31, cidx = grow >> 5;
  for (int s = 0; s < 5; ++s) {
    // stage B: W[:, s*128 .. s*128+128)
#pragma unroll
    for (int cc = 0; cc < 8; ++cc) {
      int ch = cc*256 + tid;
      int r = ch >> 4, h0 = (ch & 15) * 8;
      *(short8*)&Bsl[r][h0] = *(const short8*)&W[(size_t)r*KTOT + s*128 + h0];
    }
    __syncthreads();
#pragma unroll
    for (int ks = 0; ks < 4; ++ks) {
      int k0 = ks*32 + lq*8;
      short8 a;
      if (s < 4) {
        int n = ((s & 1) << 7) + k0;
        short8 loc = *(const short8*)&preL[(size_t)grow*NPRE + s*128 + k0];
        uint4 lp0 = *(const uint4*)&lamPk[j32*NST + n];
        uint4 lp1 = *(const uint4*)&lamPk[j32*NST + n + 4];
        uint4 xp0 = *(const uint4*)&X0Pk[cidx*NST + n];
        uint4 xp1 = *(const uint4*)&X0Pk[cidx*NST + n + 4];
        unsigned lps[8] = {lp0.x, lp0.y, lp0.z, lp0.w, lp1.x, lp1.y, lp1.z, lp1.w};
        unsigned xps[8] = {xp0.x, xp0.y, xp0.z, xp0.w, xp1.x, xp1.y, xp1.z, xp1.w};
        unsigned short o[8];
#pragma unroll
        for (int e = 0; e < 8; ++e) {
          float lr = bits2f(lps[e] << 16);
          float li = bits2f(lps[e] & 0xFFFF0000u);
          float xr = bits2f(xps[e] << 16);
          float xi = bits2f(xps[e] & 0xFFFF0000u);
          float lv = bf2f((unsigned short)loc[e]);
          float v = (s < 2) ? (lv + lr*xr - li*xi)
                            : (lv + lr*xi + li*xr);
          o[e] = f2bf(v);
        }
        a = *(const short8*)o;
      } else {
        const float* src = u + (size_t)grow*HIN + k0;
        float4 v0 = *(const float4*)src;
        float4 v1 = *(const float4*)(src + 4);
        unsigned short o[8];
        o[0]=f2bf(v0.x); o[1]=f2bf(v0.y); o[2]=f2bf(v0.z); o[3]=f2bf(v0.w);
        o[4]=f2bf(v1.x); o[5]=f2bf(v1.y); o[6]=f2bf(v1.z); o[7]=f2bf(v1.w);
        a = *(const short8*)o;
      }
      short8 bb[8];
#pragma unroll
      for (int j = 0; j < 8; ++j) bb[j] = *(const short8*)&Bsl[j*16 + lm][k0];
#pragma unroll
      for (int j = 0; j < 8; ++j)
        acc[j] = __builtin_amdgcn_mfma_f32_16x16x32_bf16(a, bb[j], acc[j], 0, 0, 0);
    }
    __syncthreads();
  }
#pragma unroll
  for (int j = 0; j < 8; ++j)
#pragma unroll
    for (int r = 0; r < 4; ++r)
      y[(size_t)(row0 + m0 + lq*4 + r)*HOUT + j*16 + lm] = acc[j][r];
}

// --------------------------------------------------------------------------
extern "C" void kernel_launch(void* const* d_in, const int* in_sizes, int n_in,
                              void* d_out, int out_size, void* d_ws, size_t ws_size,
                              hipStream_t stream) {
  const float* u         = (const float*)d_in[0];
  const float* nu_log    = (const float*)d_in[1];
  const float* theta_log = (const float*)d_in[2];
  const float* gamma_log = (const float*)d_in[3];
  const float* B_re      = (const float*)d_in[4];
  const float* B_im      = (const float*)d_in[5];
  const float* C_re      = (const float*)d_in[6];
  const float* C_im      = (const float*)d_in[7];
  const float* Dm        = (const float*)d_in[8];
  float* y = (float*)d_out;
  char* ws = (char*)d_ws;

  size_t off = 0;
  float* lamre = (float*)(ws + off);            off += 1024;
  float* lamim = (float*)(ws + off);            off += 1024;
  unsigned* lamPk = (unsigned*)(ws + off);      off += 32768;       // 32x256 u32
  unsigned short* Wb = (unsigned short*)(ws + off); off += 131072;  // 512x128 bf16
  unsigned short* W  = (unsigned short*)(ws + off); off += 163840;  // 128x640 bf16
  unsigned short* preL = (unsigned short*)(ws + off); off += (size_t)ROWS*NPRE*2; // 64 MB
  float* S_re = (float*)(ws + off);             off += 2097152;
  float* S_im = (float*)(ws + off);             off += 2097152;
  float* G_re = (float*)(ws + off);             off += 131072;
  float* G_im = (float*)(ws + off);             off += 131072;
  unsigned* X0Pk = (unsigned*)(ws + off);       off += 2097152;     // 2048x256 u32

  k_prep<<<320, 256, 0, stream>>>(nu_log, theta_log, gamma_log, B_re, B_im,
                                  C_re, C_im, Dm, lamre, lamim, lamPk, Wb, W);
  k_bu<<<ROWS/64, 256, 0, stream>>>(u, Wb, lamre, lamim, preL, S_re, S_im);
  k_carry2<<<BATCH*8, 256, 0, stream>>>(S_re, S_im, lamre, lamim, G_re, G_im);
  k_final<<<BATCH*8, 256, 0, stream>>>(S_re, S_im, G_re, G_im, lamre, lamim, X0Pk);
  k_out2<<<ROWS/64, 256, 0, stream>>>(preL, u, W, lamPk, X0Pk, y);
}

// Round 3
// 162.906 us; speedup vs baseline: 1.0933x; 1.0933x over previous
//
#include <hip/hip_runtime.h>
#include <math.h>

// Problem constants
#define BATCH 16
#define SEQ   4096
#define HIN   128
#define NST   256
#define HOUT  128
#define CL    32              // chunk length for scan
#define NC    (SEQ/CL)        // 128 chunks
#define ROWS  (BATCH*SEQ)     // 65536
#define KTOT  640             // W K layout: 256 re + 256 im + 128 u
#define NPRE  512             // preL row width: [x_re 256 | x_im 256]

typedef __attribute__((ext_vector_type(8))) short short8;
typedef __attribute__((ext_vector_type(4))) float f32x4;

__device__ inline unsigned short f2bf(float f) {
  union { float f; unsigned u; } v; v.f = f;
  unsigned r = v.u + 0x7FFFu + ((v.u >> 16) & 1u);   // RNE
  return (unsigned short)(r >> 16);
}
__device__ inline float bf2f(unsigned short s) {
  union { unsigned u; float f; } v; v.u = ((unsigned)s) << 16;
  return v.f;
}
__device__ inline float bits2f(unsigned u) {
  union { unsigned u; float f; } v; v.u = u; return v.f;
}

// ------------------------------------------------------------- prep --------
// Wb rows PERMUTED: row r: g=r>>7, w=r&127; n = g*64 + (w&63);
//   w<64 -> gamma*B_re[n], else gamma*B_im[n].
// W = [C_re | -C_im | D] bf16 [128][640].
// lamPk[j][n] = packed bf16 (re lo, im hi) of lambda_n^j, j=0..31.
__global__ __launch_bounds__(256) void k_prep(
    const float* __restrict__ nu_log, const float* __restrict__ theta_log,
    const float* __restrict__ gamma_log,
    const float* __restrict__ Bre, const float* __restrict__ Bim,
    const float* __restrict__ Cre, const float* __restrict__ Cim,
    const float* __restrict__ Dm,
    float* __restrict__ lamre, float* __restrict__ lamim,
    unsigned* __restrict__ lamPk,
    unsigned short* __restrict__ Wb, unsigned short* __restrict__ W) {
  int idx = blockIdx.x*256 + threadIdx.x;
  if (idx < NST) {
    float lm = expf(-expf(nu_log[idx]));
    float th = expf(theta_log[idx]);
    float lr = lm * cosf(th), li = lm * sinf(th);
    lamre[idx] = lr; lamim[idx] = li;
    float pr = 1.f, pi = 0.f;
    for (int j = 0; j < CL; ++j) {
      lamPk[j*NST + idx] = ((unsigned)f2bf(pi) << 16) | (unsigned)f2bf(pr);
      float nr = pr*lr - pi*li;
      float ni = pr*li + pi*lr;
      pr = nr; pi = ni;
    }
  }
  if (idx < 512*HIN) {
    int r = idx >> 7, h = idx & 127;
    int g = r >> 7;
    int w = r & 127;
    int n = g*64 + (w & 63);
    float gm = expf(gamma_log[n]);
    float v = (w < 64) ? Bre[n*HIN + h] : Bim[n*HIN + h];
    Wb[idx] = f2bf(gm * v);
  }
  if (idx < HOUT*KTOT) {
    int o = idx / KTOT, k = idx - o*KTOT;
    float v;
    if (k < NST)        v =  Cre[o*NST + k];
    else if (k < 2*NST) v = -Cim[o*NST + (k - NST)];
    else                v =  Dm[o*HIN + (k - 2*NST)];
    W[idx] = f2bf(v);
  }
}

// -------- bu GEMM (MFMA) + fused local-prefix + chunk-carry epilogue -------
// grid ROWS/128 = 512. Block: 128 rows x 512 cols (4 col-groups).
// Reads u f32 directly (converts during staging). Emits preL (bf16 local
// prefix states) + S_re/S_im (f32 chunk carries). bu never materialized.
// (EXACT round-0 text — harness-verified at 173 us.)
union SharedBu {
  unsigned short B[128][136];   // 34.8 KB group staging
  float stg[2][32][132];        // 33.8 KB carry stage
};
__global__ __launch_bounds__(256) void k_bu(
    const float* __restrict__ u, const unsigned short* __restrict__ Wb,
    const float* __restrict__ lamre, const float* __restrict__ lamim,
    unsigned short* __restrict__ preL,
    float* __restrict__ S_re, float* __restrict__ S_im) {
  __shared__ unsigned short Asl[128][136];   // resident whole kernel
  __shared__ SharedBu sh;
  int tid = threadIdx.x;
  int row0 = blockIdx.x * 128;
  int wid = tid >> 6, lane = tid & 63;
  int lm = lane & 15, lq = lane >> 4;
  int m0 = (wid >> 1) * 64, n0 = (wid & 1) * 64;
  int b = row0 >> 12;                 // / SEQ
  int cbase = (row0 & 4095) >> 5;     // / CL
  // stage A: 128 rows x 128 f32 -> bf16
#pragma unroll
  for (int cc = 0; cc < 8; ++cc) {
    int ch = cc*256 + tid;
    int r = ch >> 4, h0 = (ch & 15) * 8;
    const float* src = u + (size_t)(row0 + r)*HIN + h0;
    float4 v0 = *(const float4*)src;
    float4 v1 = *(const float4*)(src + 4);
    unsigned short o[8];
    o[0]=f2bf(v0.x); o[1]=f2bf(v0.y); o[2]=f2bf(v0.z); o[3]=f2bf(v0.w);
    o[4]=f2bf(v1.x); o[5]=f2bf(v1.y); o[6]=f2bf(v1.z); o[7]=f2bf(v1.w);
    *(short8*)&Asl[r][h0] = *(const short8*)o;
  }
  for (int g = 0; g < 4; ++g) {
    __syncthreads();    // A ready (g=0) / prior carry reads done (g>0)
#pragma unroll
    for (int cc = 0; cc < 8; ++cc) {
      int ch = cc*256 + tid;
      int r = ch >> 4, h0 = (ch & 15) * 8;
      *(short8*)&sh.B[r][h0] = *(const short8*)&Wb[(size_t)(g*128 + r)*HIN + h0];
    }
    __syncthreads();
    f32x4 acc[4][4];
#pragma unroll
    for (int i = 0; i < 4; ++i)
#pragma unroll
      for (int j = 0; j < 4; ++j) acc[i][j] = (f32x4)0.f;
#pragma unroll
    for (int ks = 0; ks < 4; ++ks) {
      int k0 = ks*32 + lq*8;
      short8 a[4], bb[4];
#pragma unroll
      for (int i = 0; i < 4; ++i) a[i] = *(const short8*)&Asl[m0 + i*16 + lm][k0];
#pragma unroll
      for (int j = 0; j < 4; ++j) bb[j] = *(const short8*)&sh.B[n0 + j*16 + lm][k0];
#pragma unroll
      for (int i = 0; i < 4; ++i)
#pragma unroll
        for (int j = 0; j < 4; ++j)
          acc[i][j] = __builtin_amdgcn_mfma_f32_16x16x32_bf16(a[i], bb[j], acc[i][j], 0, 0, 0);
    }
    // epilogue: per chunk-pair, stage acc to LDS, serial scan emitting
    // local prefix states (bf16) + final carry (f32).
    for (int p = 0; p < 2; ++p) {
      __syncthreads();   // B reads done (p=0) / prior scan reads done (p=1)
#pragma unroll
      for (int ii = 0; ii < 2; ++ii) {
        int i = 2*p + ii;
#pragma unroll
        for (int j = 0; j < 4; ++j)
#pragma unroll
          for (int r = 0; r < 4; ++r) {
            int trow = ii*16 + lq*4 + r;            // 0..31 within chunk
            sh.stg[wid >> 1][trow][n0 + j*16 + lm] = acc[i][j][r];
          }
      }
      __syncthreads();
      if (tid < 128) {
        int buf = tid >> 6, nl = tid & 63;
        int ng = g*64 + nl;
        float lr = lamre[ng], li = lamim[ng];
        float rr[CL], ri[CL];
#pragma unroll
        for (int t = 0; t < CL; ++t) {
          rr[t] = sh.stg[buf][t][nl];
          ri[t] = sh.stg[buf][t][64 + nl];
        }
        int rowb = row0 + buf*64 + p*32;
        unsigned short* pl = preL + (size_t)rowb*NPRE;
        float sr = 0.f, si = 0.f;
#pragma unroll
        for (int t = 0; t < CL; ++t) {
          pl[ng]       = f2bf(sr);     // local prefix BEFORE step t
          pl[NST + ng] = f2bf(si);
          float nr = lr*sr - li*si + rr[t];
          float ni = lr*si + li*sr + ri[t];
          sr = nr; si = ni; pl += NPRE;
        }
        int c = cbase + buf*2 + p;
        int idx = (b*NC + c)*NST + ng;
        S_re[idx] = sr; S_im[idx] = si;
      }
    }
  }
}

// ---------------- two-level scan of chunk carries -> X0 --------------------
// level 1: carries over groups of 16 chunks. grid BATCH*8, block 256.
// (round-1 text — harness-verified.)
__global__ __launch_bounds__(256) void k_carry2(
    const float* __restrict__ S_re, const float* __restrict__ S_im,
    const float* __restrict__ lamre, const float* __restrict__ lamim,
    float* __restrict__ G_re, float* __restrict__ G_im) {
  int blk = blockIdx.x;
  int b = blk >> 3, g = blk & 7;
  int n = threadIdx.x;
  float ar = lamre[n], ai = lamim[n];
#pragma unroll
  for (int s = 0; s < 5; ++s) { float nr = ar*ar - ai*ai, ni = 2.f*ar*ai; ar = nr; ai = ni; } // lam^32
  float sre[16], sim[16];
#pragma unroll
  for (int cc = 0; cc < 16; ++cc) {
    int idx = (b*NC + g*16 + cc)*NST + n;
    sre[cc] = S_re[idx]; sim[cc] = S_im[idx];
  }
  float tr = 0.f, ti = 0.f;
#pragma unroll
  for (int cc = 0; cc < 16; ++cc) {
    float nr = ar*tr - ai*ti + sre[cc];
    float ni = ar*ti + ai*tr + sim[cc];
    tr = nr; ti = ni;
  }
  int gi = (b*8 + g)*NST + n;
  G_re[gi] = tr; G_im[gi] = ti;
}

// level 2: group prefix then per-chunk X0 (packed bf16). grid BATCH*8.
// (round-1 text — harness-verified.)
__global__ __launch_bounds__(256) void k_final(
    const float* __restrict__ S_re, const float* __restrict__ S_im,
    const float* __restrict__ G_re, const float* __restrict__ G_im,
    const float* __restrict__ lamre, const float* __restrict__ lamim,
    unsigned* __restrict__ X0Pk) {
  int blk = blockIdx.x;
  int b = blk >> 3, g = blk & 7;
  int n = threadIdx.x;
  float ar = lamre[n], ai = lamim[n];
#pragma unroll
  for (int s = 0; s < 5; ++s) { float nr = ar*ar - ai*ai, ni = 2.f*ar*ai; ar = nr; ai = ni; } // lam^32
  float a5r = ar, a5i = ai;
#pragma unroll
  for (int s = 0; s < 4; ++s) { float nr = a5r*a5r - a5i*a5i, ni = 2.f*a5r*a5i; a5r = nr; a5i = ni; } // lam^512
  float gr_[7], gi_[7];
#pragma unroll
  for (int j = 0; j < 7; ++j) {
    if (j < g) { int gi2 = (b*8 + j)*NST + n; gr_[j] = G_re[gi2]; gi_[j] = G_im[gi2]; }
    else       { gr_[j] = 0.f; gi_[j] = 0.f; }
  }
  float pr = 0.f, pi = 0.f;
#pragma unroll
  for (int j = 0; j < 7; ++j) {
    if (j < g) {
      float nr = a5r*pr - a5i*pi + gr_[j];
      float ni = a5r*pi + a5i*pr + gi_[j];
      pr = nr; pi = ni;
    }
  }
  float sre[16], sim[16];
#pragma unroll
  for (int cc = 0; cc < 16; ++cc) {
    int idx = (b*NC + g*16 + cc)*NST + n;
    sre[cc] = S_re[idx]; sim[cc] = S_im[idx];
  }
  float xr = pr, xi = pi;
#pragma unroll
  for (int cc = 0; cc < 16; ++cc) {
    int idx = (b*NC + g*16 + cc)*NST + n;
    X0Pk[idx] = ((unsigned)f2bf(xi) << 16) | (unsigned)f2bf(xr);
    float nr = ar*xr - ai*xi + sre[cc];
    float ni = ar*xi + ai*xr + sim[cc];
    xr = nr; xi = ni;
  }
}

// -------------- output GEMM: LDS-staged A with fix-up at staging -----------
// y[128 rows][128 o] = [fix(preL) | u] @ W^T.  grid ROWS/128 = 512.
// ONLY change vs round-0: A is staged through LDS with coalesced loads and
// the lam^j * X0 fix-up applied at staging time (per-element fix-up block
// copied verbatim from the PASSING round-1 kernel; data formats unchanged).
// Replaces round-0's per-fragment 16-row gathers (preL + lamPk) that
// dominated latency. LDS 69.6 KB (same budget as k_bu, proven fine).
__global__ __launch_bounds__(256) void k_out2(
    const unsigned short* __restrict__ preL, const float* __restrict__ u,
    const unsigned short* __restrict__ W,
    const unsigned* __restrict__ lamPk, const unsigned* __restrict__ X0Pk,
    float* __restrict__ y) {
  __shared__ unsigned short Asl[128][136];
  __shared__ unsigned short Bsl[128][136];
  int tid = threadIdx.x;
  int row0 = blockIdx.x * 128;
  int wid = tid >> 6, lane = tid & 63;
  int lm = lane & 15, lq = lane >> 4;
  int m0 = wid * 32;
  f32x4 acc[2][8];
#pragma unroll
  for (int i = 0; i < 2; ++i)
#pragma unroll
    for (int j = 0; j < 8; ++j) acc[i][j] = (f32x4)0.f;
  for (int s = 0; s < 5; ++s) {
    __syncthreads();   // prior MFMA LDS reads done before restage
    // stage B: W[:, s*128 .. s*128+128)
#pragma unroll
    for (int cc = 0; cc < 8; ++cc) {
      int ch = cc*256 + tid;
      int r = ch >> 4, h0 = (ch & 15) * 8;
      *(short8*)&Bsl[r][h0] = *(const short8*)&W[(size_t)r*KTOT + s*128 + h0];
    }
    // stage A: 128 rows x 128 cols, coalesced, fix-up applied inline
    if (s < 4) {
#pragma unroll
      for (int cc = 0; cc < 8; ++cc) {
        int ch = cc*256 + tid;
        int r = ch >> 4, h0 = (ch & 15) * 8;
        int grow = row0 + r;
        int j32 = r & 31;            // row0 % 128 == 0
        int cidx = grow >> 5;
        int n = ((s & 1) << 7) + h0; // state index of first element
        short8 loc = *(const short8*)&preL[(size_t)grow*NPRE + s*128 + h0];
        uint4 lp0 = *(const uint4*)&lamPk[j32*NST + n];
        uint4 lp1 = *(const uint4*)&lamPk[j32*NST + n + 4];
        uint4 xp0 = *(const uint4*)&X0Pk[(size_t)cidx*NST + n];
        uint4 xp1 = *(const uint4*)&X0Pk[(size_t)cidx*NST + n + 4];
        unsigned lps[8] = {lp0.x, lp0.y, lp0.z, lp0.w, lp1.x, lp1.y, lp1.z, lp1.w};
        unsigned xps[8] = {xp0.x, xp0.y, xp0.z, xp0.w, xp1.x, xp1.y, xp1.z, xp1.w};
        unsigned short o[8];
#pragma unroll
        for (int e = 0; e < 8; ++e) {
          float lr = bits2f(lps[e] << 16);
          float li = bits2f(lps[e] & 0xFFFF0000u);
          float xr = bits2f(xps[e] << 16);
          float xi = bits2f(xps[e] & 0xFFFF0000u);
          float lv = bf2f((unsigned short)loc[e]);
          float v = (s < 2) ? (lv + lr*xr - li*xi)
                            : (lv + lr*xi + li*xr);
          o[e] = f2bf(v);
        }
        *(short8*)&Asl[r][h0] = *(const short8*)o;
      }
    } else {
#pragma unroll
      for (int cc = 0; cc < 8; ++cc) {
        int ch = cc*256 + tid;
        int r = ch >> 4, h0 = (ch & 15) * 8;
        const float* src = u + (size_t)(row0 + r)*HIN + h0;
        float4 v0 = *(const float4*)src;
        float4 v1 = *(const float4*)(src + 4);
        unsigned short o[8];
        o[0]=f2bf(v0.x); o[1]=f2bf(v0.y); o[2]=f2bf(v0.z); o[3]=f2bf(v0.w);
        o[4]=f2bf(v1.x); o[5]=f2bf(v1.y); o[6]=f2bf(v1.z); o[7]=f2bf(v1.w);
        *(short8*)&Asl[r][h0] = *(const short8*)o;
      }
    }
    __syncthreads();
#pragma unroll
    for (int ks = 0; ks < 4; ++ks) {
      int k0 = ks*32 + lq*8;
      short8 a[2], bb[8];
#pragma unroll
      for (int i = 0; i < 2; ++i) a[i] = *(const short8*)&Asl[m0 + i*16 + lm][k0];
#pragma unroll
      for (int j = 0; j < 8; ++j) bb[j] = *(const short8*)&Bsl[j*16 + lm][k0];
#pragma unroll
      for (int i = 0; i < 2; ++i)
#pragma unroll
        for (int j = 0; j < 8; ++j)
          acc[i][j] = __builtin_amdgcn_mfma_f32_16x16x32_bf16(a[i], bb[j], acc[i][j], 0, 0, 0);
    }
  }
#pragma unroll
  for (int i = 0; i < 2; ++i)
#pragma unroll
    for (int j = 0; j < 8; ++j)
#pragma unroll
      for (int r = 0; r < 4; ++r)
        y[(size_t)(row0 + m0 + i*16 + lq*4 + r)*HOUT + j*16 + lm] = acc[i][j][r];
}

// --------------------------------------------------------------------------
extern "C" void kernel_launch(void* const* d_in, const int* in_sizes, int n_in,
                              void* d_out, int out_size, void* d_ws, size_t ws_size,
                              hipStream_t stream) {
  const float* u         = (const float*)d_in[0];
  const float* nu_log    = (const float*)d_in[1];
  const float* theta_log = (const float*)d_in[2];
  const float* gamma_log = (const float*)d_in[3];
  const float* B_re      = (const float*)d_in[4];
  const float* B_im      = (const float*)d_in[5];
  const float* C_re      = (const float*)d_in[6];
  const float* C_im      = (const float*)d_in[7];
  const float* Dm        = (const float*)d_in[8];
  float* y = (float*)d_out;
  char* ws = (char*)d_ws;

  size_t off = 0;
  float* lamre = (float*)(ws + off);            off += 1024;
  float* lamim = (float*)(ws + off);            off += 1024;
  unsigned* lamPk = (unsigned*)(ws + off);      off += 32768;       // 32x256 u32
  unsigned short* Wb = (unsigned short*)(ws + off); off += 131072;  // 512x128 bf16
  unsigned short* W  = (unsigned short*)(ws + off); off += 163840;  // 128x640 bf16
  unsigned short* preL = (unsigned short*)(ws + off); off += (size_t)ROWS*NPRE*2; // 64 MB
  float* S_re = (float*)(ws + off);             off += 2097152;
  float* S_im = (float*)(ws + off);             off += 2097152;
  float* G_re = (float*)(ws + off);             off += 131072;
  float* G_im = (float*)(ws + off);             off += 131072;
  unsigned* X0Pk = (unsigned*)(ws + off);       off += 2097152;     // 2048x256 u32

  k_prep<<<320, 256, 0, stream>>>(nu_log, theta_log, gamma_log, B_re, B_im,
                                  C_re, C_im, Dm, lamre, lamim, lamPk, Wb, W);
  k_bu<<<ROWS/128, 256, 0, stream>>>(u, Wb, lamre, lamim, preL, S_re, S_im);
  k_carry2<<<BATCH*8, 256, 0, stream>>>(S_re, S_im, lamre, lamim, G_re, G_im);
  k_final<<<BATCH*8, 256, 0, stream>>>(S_re, S_im, G_re, G_im, lamre, lamim, X0Pk);
  k_out2<<<ROWS/128, 256, 0, stream>>>(preL, u, W, lamPk, X0Pk, y);
}